// Round 2
// baseline (3073.320 us; speedup 1.0000x reference)
//
#include <hip/hip_runtime.h>
#include <hip/hip_bf16.h>
#include <stdint.h>

typedef unsigned short u16;
typedef __attribute__((ext_vector_type(4))) float floatx4;
typedef __attribute__((ext_vector_type(8))) short bf16x8;
typedef __attribute__((ext_vector_type(8))) unsigned short u16x8;
typedef const __attribute__((address_space(1))) void gvoid;
typedef __attribute__((address_space(3))) void lvoid;

static constexpr int Mdim = 4096;   // B*S = 4*1024
static constexpr int Hdim = 5120;
static constexpr int Idim = 12288;
static constexpr float QINV = 1.0f / 127.0f;

static __device__ __forceinline__ u16 f2b(float f) {
    __hip_bfloat16 h = __float2bfloat16(f);
    return *(u16*)&h;
}

// ---- int32 -> bf16 weight conversion (values in [-127,127] are exact in bf16)
__global__ void conv_i32_to_bf16(const int* __restrict__ in, u16* __restrict__ out) {
    int idx = (blockIdx.x * 256 + threadIdx.x) * 8;
    int4 v0 = *(const int4*)(in + idx);
    int4 v1 = *(const int4*)(in + idx + 4);
    u16x8 o;
    o[0] = f2b((float)v0.x); o[1] = f2b((float)v0.y);
    o[2] = f2b((float)v0.z); o[3] = f2b((float)v0.w);
    o[4] = f2b((float)v1.x); o[5] = f2b((float)v1.y);
    o[6] = f2b((float)v1.z); o[7] = f2b((float)v1.w);
    *(u16x8*)(out + idx) = o;
}

// ---- f32 -> bf16 activation conversion
__global__ void conv_f32_to_bf16(const float* __restrict__ in, u16* __restrict__ out) {
    int idx = (blockIdx.x * 256 + threadIdx.x) * 8;
    float4 v0 = *(const float4*)(in + idx);
    float4 v1 = *(const float4*)(in + idx + 4);
    u16x8 o;
    o[0] = f2b(v0.x); o[1] = f2b(v0.y); o[2] = f2b(v0.z); o[3] = f2b(v0.w);
    o[4] = f2b(v1.x); o[5] = f2b(v1.y); o[6] = f2b(v1.z); o[7] = f2b(v1.w);
    *(u16x8*)(out + idx) = o;
}

// ============================================================================
// 256x256-tile bf16 GEMM, C[m][n] = sum_k A[m,k]*W[n,k], fused epilogues.
// R2 restructure: ONE barrier per 32-K-tile (was 4), B-fragments read once
// per tile (was twice). Rationale (R1 post-mortem): per-CU LDS-read time
// (128 KiB/tile @85 B/cyc) exceeded MFMA time (1240 cyc) and the 4 barriers
// serialized the two pipes -> MfmaUtil capped at 29%. Now LDS = 96 KiB/tile
// (~1160 cyc) < MFMA, and waves drift within the tile window so one wave's
// ds_reads overlap another's MFMAs.
// Correctness of the single barrier (4-buffer ring, stage depth 3):
//  - RAW: vmcnt(8) before the tile-t barrier retires own tile-t stages
//    (outstanding: t,t+1,t+2 = 12 loads; newest 8 = t+1,t+2); barrier makes
//    it global; reads of buf[t] follow the barrier.
//  - WAR: stage(t+3) overwrites buf[(t-1)&3]. Every wave's tile-(t-1)
//    ds_reads are lgkmcnt-drained before its MFMA cluster (compiler-enforced
//    register dep), which precedes the tile-t barrier in program order; the
//    barrier then guarantees all waves are done before any stage issues.
// vmcnt is NEVER 0 in the main loop (T4); epilogue drains 8 -> 4 -> 0.
// LDS swizzle: 16B unit u of row r holds global chunk u ^ ((r>>1)&3), applied
// on the global_load_lds SOURCE (dest linear, m104/m173) and on the ds_read
// address. 2-way bank aliasing = free (m136).
// Waves: 8 (2M x 4N), wave tile 128x64, acc[8][4] floatx4.
// MODE 0: GateBuf = bf16(silu(acc*s))        (gate projection)
// MODE 1: GateBuf = bf16(GateBuf * acc*s)    (up projection, in-place gate*up)
// MODE 2: OutF    = acc*s                    (down projection, fp32 out)
// ============================================================================
template<int MODE>
__global__ __launch_bounds__(512, 2)
void gemm256(const u16* __restrict__ A, const u16* __restrict__ Bw,
             const float* __restrict__ scale, u16* __restrict__ GateBuf,
             float* __restrict__ OutF, int N, int K, int nbx)
{
    __shared__ u16 As[4 * 8192];   // 4 buffers x 256 rows x 32 elems (64 KiB)
    __shared__ u16 Bs[4 * 8192];   // 64 KiB

    const int tid  = threadIdx.x;
    const int lane = tid & 63;
    const int wave = tid >> 6;
    const int wm = (wave >> 2) * 128;   // wave row offset in tile (2 M-waves)
    const int wn = (wave & 3) * 64;     // wave col offset in tile (4 N-waves)
    const int lm = lane & 15;
    const int lg = lane >> 4;           // which 8-elem K chunk

    // T1: bijective XCD swizzle (nwg % 8 == 0 for all launches here).
    const int nwg = gridDim.x;
    const int bid = blockIdx.x;
    const int swz = (bid & 7) * (nwg >> 3) + (bid >> 3);
    const int row0 = (swz % nbx) * 256;
    const int col0 = (swz / nbx) * 256;

    const u16* Ablk = A  + (size_t)row0 * K;
    const u16* Bblk = Bw + (size_t)col0 * K;

    // staging: thread owns 16B unit tid (row rs, unit u) and the mirror at
    // row rs+128 (same swizzle: (r+128)>>1 keeps the low bits).
    const int rs  = tid >> 2;
    const int csw = ((tid & 3) ^ ((rs >> 1) & 3)) << 3;   // swizzled elem offset
    const u16* aS = Ablk + (size_t)rs * K + csw;
    const u16* bS = Bblk + (size_t)rs * K + csw;
    const size_t rK128 = (size_t)128 * K;
    u16* aD = As + tid * 8;
    u16* bD = Bs + tid * 8;

    // ds_read swizzle: row = 16*frag + lm, so x(row) = (lm>>1)&3
    const int koff = (lg ^ ((lm >> 1) & 3)) << 3;

    floatx4 acc[8][4];
    #pragma unroll
    for (int i = 0; i < 8; i++)
        #pragma unroll
        for (int j = 0; j < 4; j++)
            acc[i][j] = (floatx4){0.f, 0.f, 0.f, 0.f};

    const int nt = K >> 5;   // K-tiles of 32

#define STAGE(t) do { \
    const u16* sA_ = aS + (size_t)(t) * 32; \
    const u16* sB_ = bS + (size_t)(t) * 32; \
    u16* dA_ = aD + ((t) & 3) * 8192; \
    u16* dB_ = bD + ((t) & 3) * 8192; \
    __builtin_amdgcn_global_load_lds((gvoid*)sA_, (lvoid*)dA_, 16, 0, 0); \
    __builtin_amdgcn_global_load_lds((gvoid*)(sA_ + rK128), (lvoid*)(dA_ + 4096), 16, 0, 0); \
    __builtin_amdgcn_global_load_lds((gvoid*)sB_, (lvoid*)dB_, 16, 0, 0); \
    __builtin_amdgcn_global_load_lds((gvoid*)(sB_ + rK128), (lvoid*)(dB_ + 4096), 16, 0, 0); \
} while (0)

// one K-tile: B frags once, then two A-quadrant MFMA clusters (T5 setprio).
// No internal barriers: compiler interleaves ds_reads/MFMA with fine lgkmcnt.
#define COMPUTE(t) do { \
    const int bufo = ((t) & 3) * 8192; \
    const u16* Ab_ = As + bufo; \
    const u16* Bb_ = Bs + bufo; \
    bf16x8 bf[4]; \
    _Pragma("unroll") \
    for (int j = 0; j < 4; j++) \
        bf[j] = *(const bf16x8*)(Bb_ + (wn + j * 16 + lm) * 32 + koff); \
    _Pragma("unroll") \
    for (int q = 0; q < 2; q++) { \
        bf16x8 af[4]; \
        _Pragma("unroll") \
        for (int i = 0; i < 4; i++) \
            af[i] = *(const bf16x8*)(Ab_ + (wm + (q * 4 + i) * 16 + lm) * 32 + koff); \
        __builtin_amdgcn_s_setprio(1); \
        _Pragma("unroll") \
        for (int i = 0; i < 4; i++) \
            _Pragma("unroll") \
            for (int j = 0; j < 4; j++) \
                acc[q * 4 + i][j] = __builtin_amdgcn_mfma_f32_16x16x32_bf16( \
                    af[i], bf[j], acc[q * 4 + i][j], 0, 0, 0); \
        __builtin_amdgcn_s_setprio(0); \
    } \
} while (0)

    // prologue: stage tiles 0,1,2 (12 loads, 3-deep)
    STAGE(0); STAGE(1); STAGE(2);

    int t = 0;
    for (; t < nt - 3; ++t) {
        asm volatile("s_waitcnt vmcnt(8)" ::: "memory");
        __builtin_amdgcn_s_barrier();
        asm volatile("" ::: "memory");
        STAGE(t + 3);
        COMPUTE(t);
    }
    // peeled drain: outstanding own-loads at barrier of tile t are the stages
    // for t..t+2 that were actually issued -> 12, 8, 4 loads respectively.
    asm volatile("s_waitcnt vmcnt(8)" ::: "memory");
    __builtin_amdgcn_s_barrier();
    asm volatile("" ::: "memory");
    COMPUTE(nt - 3);
    asm volatile("s_waitcnt vmcnt(4)" ::: "memory");
    __builtin_amdgcn_s_barrier();
    asm volatile("" ::: "memory");
    COMPUTE(nt - 2);
    asm volatile("s_waitcnt vmcnt(0)" ::: "memory");
    __builtin_amdgcn_s_barrier();
    asm volatile("" ::: "memory");
    COMPUTE(nt - 1);
#undef COMPUTE
#undef STAGE

    // epilogue: C/D layout col=lane&15, row=(lane>>4)*4+reg   [m89-verified]
    const int ln = lane & 15;
    const int rq = (lane >> 4) * 4;
    #pragma unroll
    for (int j = 0; j < 4; j++) {
        const int col = col0 + wn + j * 16 + ln;
        const float s = scale[col] * QINV;
        #pragma unroll
        for (int i = 0; i < 8; i++) {
            const int rowb = row0 + wm + i * 16 + rq;
            #pragma unroll
            for (int r = 0; r < 4; r++) {
                const size_t idx = (size_t)(rowb + r) * N + col;
                float v = acc[i][j][r] * s;
                if (MODE == 0) {
                    float g = v / (1.0f + __expf(-v));   // silu
                    GateBuf[idx] = f2b(g);
                } else if (MODE == 1) {
                    u16 gu = GateBuf[idx];
                    float g = __bfloat162float(*(__hip_bfloat16*)&gu);
                    GateBuf[idx] = f2b(g * v);
                } else {
                    OutF[idx] = v;
                }
            }
        }
    }
}

extern "C" void kernel_launch(void* const* d_in, const int* in_sizes, int n_in,
                              void* d_out, int out_size, void* d_ws, size_t ws_size,
                              hipStream_t stream)
{
    const float* x  = (const float*)d_in[0];
    const int*   wg = (const int*)d_in[1];
    const float* sg = (const float*)d_in[2];
    const int*   wu = (const int*)d_in[3];
    const float* su = (const float*)d_in[4];
    const int*   wd = (const int*)d_in[5];
    const float* sd = (const float*)d_in[6];
    float* out = (float*)d_out;

    char* ws = (char*)d_ws;
    u16* xb   = (u16*)ws;                                        // 4096*5120 bf16   (42 MB)
    u16* wb   = (u16*)(ws + 41943040);                           // 62914560 bf16    (126 MB, reused 3x)
    u16* gate = (u16*)(ws + 41943040 + 125829120);               // 4096*12288 bf16  (100 MB, gate then h)

    // x: 20971520 elems / 2048 per block
    conv_f32_to_bf16<<<10240, 256, 0, stream>>>(x, xb);

    // gate = silu((x @ Wg^T) * sg/127)
    conv_i32_to_bf16<<<30720, 256, 0, stream>>>(wg, wb);
    gemm256<0><<<(Mdim / 256) * (Idim / 256), 512, 0, stream>>>(
        xb, wb, sg, gate, nullptr, Idim, Hdim, Mdim / 256);

    // h = gate * ((x @ Wu^T) * su/127)   (in-place over gate)
    conv_i32_to_bf16<<<30720, 256, 0, stream>>>(wu, wb);
    gemm256<1><<<(Mdim / 256) * (Idim / 256), 512, 0, stream>>>(
        xb, wb, su, gate, nullptr, Idim, Hdim, Mdim / 256);

    // out = (h @ Wd^T) * sd/127
    conv_i32_to_bf16<<<30720, 256, 0, stream>>>(wd, wb);
    gemm256<2><<<(Mdim / 256) * (Hdim / 256), 512, 0, stream>>>(
        gate, wb, sd, nullptr, out, Hdim, Idim, Mdim / 256);
}

// Round 3
// 2350.374 us; speedup vs baseline: 1.3076x; 1.3076x over previous
//
#include <hip/hip_runtime.h>
#include <hip/hip_bf16.h>
#include <stdint.h>

typedef unsigned short u16;
typedef __attribute__((ext_vector_type(4))) float floatx4;
typedef __attribute__((ext_vector_type(8))) short bf16x8;
typedef __attribute__((ext_vector_type(8))) unsigned short u16x8;
typedef const __attribute__((address_space(1))) void gvoid;
typedef __attribute__((address_space(3))) void lvoid;
typedef __attribute__((address_space(3))) u16 lu16;

static constexpr int Mdim = 4096;   // B*S = 4*1024
static constexpr int Hdim = 5120;
static constexpr int Idim = 12288;
static constexpr float QINV = 1.0f / 127.0f;

static __device__ __forceinline__ u16 f2b(float f) {
    __hip_bfloat16 h = __float2bfloat16(f);
    return *(u16*)&h;
}

// ---- int32 -> bf16 weight conversion (values in [-127,127] are exact in bf16)
__global__ void conv_i32_to_bf16(const int* __restrict__ in, u16* __restrict__ out) {
    int idx = (blockIdx.x * 256 + threadIdx.x) * 8;
    int4 v0 = *(const int4*)(in + idx);
    int4 v1 = *(const int4*)(in + idx + 4);
    u16x8 o;
    o[0] = f2b((float)v0.x); o[1] = f2b((float)v0.y);
    o[2] = f2b((float)v0.z); o[3] = f2b((float)v0.w);
    o[4] = f2b((float)v1.x); o[5] = f2b((float)v1.y);
    o[6] = f2b((float)v1.z); o[7] = f2b((float)v1.w);
    *(u16x8*)(out + idx) = o;
}

// ---- f32 -> bf16 activation conversion
__global__ void conv_f32_to_bf16(const float* __restrict__ in, u16* __restrict__ out) {
    int idx = (blockIdx.x * 256 + threadIdx.x) * 8;
    float4 v0 = *(const float4*)(in + idx);
    float4 v1 = *(const float4*)(in + idx + 4);
    u16x8 o;
    o[0] = f2b(v0.x); o[1] = f2b(v0.y); o[2] = f2b(v0.z); o[3] = f2b(v0.w);
    o[4] = f2b(v1.x); o[5] = f2b(v1.y); o[6] = f2b(v1.z); o[7] = f2b(v1.w);
    *(u16x8*)(out + idx) = o;
}

// ============================================================================
// 256x256-tile bf16 GEMM, BK=64, m201-style 4-phase schedule with ASM ds_reads.
//
// R3 theory: R1/R2's counted vmcnt was defeated by compiler-inserted drains —
// C-level __shared__ reads may-alias outstanding global_load_lds DMA writes,
// forcing conservative vmcnt waits before every phase's ds_reads (per-tile
// time ~ MFMA + full HBM latency, matching R1/R2 measurements). Fix: ALL
// fragment reads are inline-asm ds_read_b128 (invisible to alias analysis);
// the ONLY vmcnt waits in the K-loop are the counted ones below (T4), with
// rule-#18 fencing (lgkmcnt(0) + sched_barrier(0)) before each MFMA cluster.
//
// Schedule per K-tile t (parity p=t&1; buffers A[2][256][64]@0, B@64KiB):
//   ph0 (qm=0,kh=0): 8 dsr; stage B-quarters 0-3 of t+1 -> buf p^1;
//                    bar; lgkm0; 16 MFMA; vmcnt(4); bar
//   ph1 (qm=64,kh=0): 4 dsr (B regs reused); stage A-q{0,2}; bar; MFMA; bar
//   ph2 (qm=0,kh=1): 8 dsr; stage A-q{1,3}; bar; MFMA; bar
//   ph3 (qm=64,kh=1): 4 dsr; bar; MFMA; vmcnt(2); bar
// vmcnt ledger (per-wave, 8 stage loads/tile): end-ph0 vmcnt(4) retires prev
// tile's ph2 stages (this tile's A1,A3, read in ph1); end-ph3 vmcnt(2)
// retires this tile's ph0-ph1 stages (next tile's B + A0,A2, read in ph0/ph2).
// Never 0 in the main loop; prefetch distance >= 2 phases (~HBM latency).
// Race-free: reads touch buf[p] only, DMA writes buf[p^1] only; the previous
// occupant of buf[p^1] (tile t-1) was last read before >=2 barriers ago.
// LDS swizzle (bank-conflict-free, measured 0 in R1/R2): 16B unit u of row r
// holds global k-chunk u ^ (r&7); applied on DMA source + read address.
//
// MODE 0: GateBuf = bf16(silu(acc*s));  MODE 1: GateBuf *= acc*s (in place);
// MODE 2: OutF = acc*s.
// ============================================================================

#define MM(a,b,c) __builtin_amdgcn_mfma_f32_16x16x32_bf16(a, b, c, 0, 0, 0)

#define MF16(B) do { \
    acc[(B)+0][0]=MM(af0,bf0,acc[(B)+0][0]); acc[(B)+0][1]=MM(af0,bf1,acc[(B)+0][1]); \
    acc[(B)+0][2]=MM(af0,bf2,acc[(B)+0][2]); acc[(B)+0][3]=MM(af0,bf3,acc[(B)+0][3]); \
    acc[(B)+1][0]=MM(af1,bf0,acc[(B)+1][0]); acc[(B)+1][1]=MM(af1,bf1,acc[(B)+1][1]); \
    acc[(B)+1][2]=MM(af1,bf2,acc[(B)+1][2]); acc[(B)+1][3]=MM(af1,bf3,acc[(B)+1][3]); \
    acc[(B)+2][0]=MM(af2,bf0,acc[(B)+2][0]); acc[(B)+2][1]=MM(af2,bf1,acc[(B)+2][1]); \
    acc[(B)+2][2]=MM(af2,bf2,acc[(B)+2][2]); acc[(B)+2][3]=MM(af2,bf3,acc[(B)+2][3]); \
    acc[(B)+3][0]=MM(af3,bf0,acc[(B)+3][0]); acc[(B)+3][1]=MM(af3,bf1,acc[(B)+3][1]); \
    acc[(B)+3][2]=MM(af3,bf2,acc[(B)+3][2]); acc[(B)+3][3]=MM(af3,bf3,acc[(B)+3][3]); \
} while (0)

// inline-asm LDS read: addr = 32-bit LDS byte address, off = literal bytes
#define DSR(dst, addr, off) \
    asm volatile("ds_read_b128 %0, %1 offset:" #off : "=v"(dst) : "v"(addr))

#define PH_PRE() do { \
    __builtin_amdgcn_s_barrier(); \
    asm volatile("s_waitcnt lgkmcnt(0)" ::: "memory"); \
    __builtin_amdgcn_sched_barrier(0); \
    __builtin_amdgcn_s_setprio(1); \
} while (0)

#define PH_POST() do { \
    __builtin_amdgcn_s_setprio(0); \
    __builtin_amdgcn_sched_barrier(0); \
} while (0)

#define VMW(N) asm volatile("s_waitcnt vmcnt(" #N ")" ::: "memory")
#define BAR()  __builtin_amdgcn_s_barrier()

template<int MODE>
__global__ __launch_bounds__(512, 2)
void gemm256(const u16* __restrict__ A, const u16* __restrict__ Bw,
             const float* __restrict__ scale, u16* __restrict__ GateBuf,
             float* __restrict__ OutF, int N, int K, int nbx)
{
    __shared__ __align__(16) u16 smem[65536];   // 128 KiB

    const int tid  = threadIdx.x;
    const int lane = tid & 63;
    const int wave = tid >> 6;
    const int wm = (wave >> 2) * 128;   // 2 M-waves
    const int wn = (wave & 3) * 64;     // 4 N-waves
    const int lm = lane & 15;
    const int lg = lane >> 4;
    const int lm7 = lm & 7;

    // T1: bijective XCD swizzle (all grids here are %8==0)
    const int nwg = gridDim.x;
    const int bid = blockIdx.x;
    const int swz = (bid & 7) * (nwg >> 3) + (bid >> 3);
    const int row0 = (swz % nbx) * 256;
    const int col0 = (swz / nbx) * 256;

    const u16* Ablk = A  + (size_t)row0 * K;
    const u16* Bblk = Bw + (size_t)col0 * K;

    // stage thread-consts: thread owns 16B unit (row tid>>3, unit tid&7) of
    // each 64x64 quarter; swizzled source chunk = (tid&7) ^ (row&7).
    const int rowS = tid >> 3;
    const int kofS = ((tid & 7) ^ (rowS & 7)) << 3;
    const u16* aS = Ablk + (size_t)rowS * K + kofS;
    const u16* bS = Bblk + (size_t)rowS * K + kofS;

    // LDS byte addresses for asm ds_read
    const unsigned sbase = (unsigned)(size_t)(lu16*)smem;
    const unsigned aoffR = (unsigned)((wm + lm) * 128);
    const unsigned boffR = (unsigned)((wn + lm) * 128) + 65536u;
    const unsigned ub0 = (unsigned)((lg ^ lm7) << 4);         // kh0 unit bytes
    const unsigned ub1 = (unsigned)(((4 + lg) ^ lm7) << 4);   // kh1

    floatx4 acc[8][4];
    #pragma unroll
    for (int i = 0; i < 8; i++)
        #pragma unroll
        for (int j = 0; j < 4; j++)
            acc[i][j] = (floatx4){0.f, 0.f, 0.f, 0.f};

    const int nt = K >> 6;   // BK=64 tiles; 80 or 192 here

#define STG_A(q, tt) __builtin_amdgcn_global_load_lds( \
    (gvoid*)(aS + (size_t)(q) * 64 * K + (size_t)(tt) * 64), \
    (lvoid*)(smem + (((tt) & 1) << 14) + (q) * 4096 + tid * 8), 16, 0, 0)
#define STG_B(q, tt) __builtin_amdgcn_global_load_lds( \
    (gvoid*)(bS + (size_t)(q) * 64 * K + (size_t)(tt) * 64), \
    (lvoid*)(smem + 32768 + (((tt) & 1) << 14) + (q) * 4096 + tid * 8), 16, 0, 0)

    // prologue: stage all 8 quarters of tile 0, drain once (one-time cost)
    STG_B(0, 0); STG_B(1, 0); STG_B(2, 0); STG_B(3, 0);
    STG_A(0, 0); STG_A(1, 0); STG_A(2, 0); STG_A(3, 0);
    VMW(0);
    BAR();

#define TILE(t, DOSTAGE, W0, W3) do { \
    const unsigned pb  = (unsigned)(((t) & 1) << 15); \
    const unsigned aK0 = sbase + pb + aoffR + ub0; \
    const unsigned aK1 = sbase + pb + aoffR + ub1; \
    const unsigned bK0 = sbase + pb + boffR + ub0; \
    const unsigned bK1 = sbase + pb + boffR + ub1; \
    bf16x8 af0, af1, af2, af3, bf0, bf1, bf2, bf3; \
    /* ph0: qm=0, kh=0 */ \
    DSR(af0, aK0, 0); DSR(af1, aK0, 2048); DSR(af2, aK0, 4096); DSR(af3, aK0, 6144); \
    DSR(bf0, bK0, 0); DSR(bf1, bK0, 2048); DSR(bf2, bK0, 4096); DSR(bf3, bK0, 6144); \
    if (DOSTAGE) { STG_B(0, (t)+1); STG_B(1, (t)+1); STG_B(2, (t)+1); STG_B(3, (t)+1); } \
    PH_PRE(); MF16(0); PH_POST(); \
    W0; BAR(); \
    /* ph1: qm=64, kh=0 (bf reuse) */ \
    DSR(af0, aK0, 8192); DSR(af1, aK0, 10240); DSR(af2, aK0, 12288); DSR(af3, aK0, 14336); \
    if (DOSTAGE) { STG_A(0, (t)+1); STG_A(2, (t)+1); } \
    PH_PRE(); MF16(4); PH_POST(); \
    BAR(); \
    /* ph2: qm=0, kh=1 */ \
    DSR(af0, aK1, 0); DSR(af1, aK1, 2048); DSR(af2, aK1, 4096); DSR(af3, aK1, 6144); \
    DSR(bf0, bK1, 0); DSR(bf1, bK1, 2048); DSR(bf2, bK1, 4096); DSR(bf3, bK1, 6144); \
    if (DOSTAGE) { STG_A(1, (t)+1); STG_A(3, (t)+1); } \
    PH_PRE(); MF16(0); PH_POST(); \
    BAR(); \
    /* ph3: qm=64, kh=1 */ \
    DSR(af0, aK1, 8192); DSR(af1, aK1, 10240); DSR(af2, aK1, 12288); DSR(af3, aK1, 14336); \
    PH_PRE(); MF16(4); PH_POST(); \
    W3; BAR(); \
} while (0)

    for (int t = 0; t < nt - 1; ++t)
        TILE(t, 1, VMW(4), VMW(2));
    // last tile: nothing to stage; drain the 2 remaining (own A1,A3) at ph0
    TILE(nt - 1, 0, VMW(0), (void)0);

#undef TILE
#undef STG_A
#undef STG_B

    // epilogue: C/D layout col=lane&15, row=(lane>>4)*4+reg   [m89-verified]
    const int ln = lane & 15;
    const int rq = (lane >> 4) * 4;
    #pragma unroll
    for (int j = 0; j < 4; j++) {
        const int col = col0 + wn + j * 16 + ln;
        const float s = scale[col] * QINV;
        #pragma unroll
        for (int i = 0; i < 8; i++) {
            const int rowb = row0 + wm + i * 16 + rq;
            #pragma unroll
            for (int r = 0; r < 4; r++) {
                const size_t idx = (size_t)(rowb + r) * N + col;
                float v = acc[i][j][r] * s;
                if (MODE == 0) {
                    float g = v / (1.0f + __expf(-v));   // silu
                    GateBuf[idx] = f2b(g);
                } else if (MODE == 1) {
                    u16 gu = GateBuf[idx];
                    float g = __bfloat162float(*(__hip_bfloat16*)&gu);
                    GateBuf[idx] = f2b(g * v);
                } else {
                    OutF[idx] = v;
                }
            }
        }
    }
}

extern "C" void kernel_launch(void* const* d_in, const int* in_sizes, int n_in,
                              void* d_out, int out_size, void* d_ws, size_t ws_size,
                              hipStream_t stream)
{
    const float* x  = (const float*)d_in[0];
    const int*   wg = (const int*)d_in[1];
    const float* sg = (const float*)d_in[2];
    const int*   wu = (const int*)d_in[3];
    const float* su = (const float*)d_in[4];
    const int*   wd = (const int*)d_in[5];
    const float* sd = (const float*)d_in[6];
    float* out = (float*)d_out;

    char* ws = (char*)d_ws;
    u16* xb   = (u16*)ws;                                        // 4096*5120 bf16   (42 MB)
    u16* wb   = (u16*)(ws + 41943040);                           // 62914560 bf16    (126 MB, reused 3x)
    u16* gate = (u16*)(ws + 41943040 + 125829120);               // 4096*12288 bf16  (100 MB, gate then h)

    conv_f32_to_bf16<<<10240, 256, 0, stream>>>(x, xb);

    // gate = silu((x @ Wg^T) * sg/127)
    conv_i32_to_bf16<<<30720, 256, 0, stream>>>(wg, wb);
    gemm256<0><<<(Mdim / 256) * (Idim / 256), 512, 0, stream>>>(
        xb, wb, sg, gate, nullptr, Idim, Hdim, Mdim / 256);

    // h = gate * ((x @ Wu^T) * su/127)   (in-place over gate)
    conv_i32_to_bf16<<<30720, 256, 0, stream>>>(wu, wb);
    gemm256<1><<<(Mdim / 256) * (Idim / 256), 512, 0, stream>>>(
        xb, wb, su, gate, nullptr, Idim, Hdim, Mdim / 256);

    // out = (h @ Wd^T) * sd/127
    conv_i32_to_bf16<<<30720, 256, 0, stream>>>(wd, wb);
    gemm256<2><<<(Mdim / 256) * (Hdim / 256), 512, 0, stream>>>(
        gate, wb, sd, nullptr, out, Hdim, Idim, Mdim / 256);
}